// Round 8
// baseline (161.020 us; speedup 1.0000x reference)
//
#include <hip/hip_runtime.h>

#define NB 8
#define NC 512
#define NTOK 1024
#define NHEADS 4
#define DKH 128

typedef unsigned short u16;
typedef __attribute__((ext_vector_type(8))) short bf16x8;   // 8 bf16 (4 VGPRs)
typedef __attribute__((ext_vector_type(4))) float f32x4;

__device__ inline u16 f2b(float f) {
    union { float f; unsigned u; } v; v.f = f;
    unsigned r = v.u + 0x7fffu + ((v.u >> 16) & 1u);   // RNE
    return (u16)(r >> 16);
}

// async global->LDS DMA, 16B per lane; LDS dest = wave-uniform base + lane*16
__device__ __forceinline__ void gll16(const u16* g, u16* l) {
    __builtin_amdgcn_global_load_lds((const __attribute__((address_space(1))) unsigned*)g,
                                     (__attribute__((address_space(3))) unsigned*)l, 16, 0, 0);
}

// ---- fused prep: 3 transpose+convert jobs in one launch ----
// z=0: Wp[512][1536] -> WpT[1536][512]; z=1: Wo[512][512] -> WoT[512][512];
// z>=2: x batch (z-2) [512][1024] -> xsb [1024][512]
__global__ __launch_bounds__(256) void prep(const float* __restrict__ x, const float* __restrict__ Wp,
                                            const float* __restrict__ Wo,
                                            u16* __restrict__ xsb, u16* __restrict__ WpT, u16* __restrict__ WoT)
{
    __shared__ float tile[32][33];
    const int z = blockIdx.z;
    const float* src; u16* dst; int R, Cc;
    if (z == 0)      { src = Wp; dst = WpT; R = 512; Cc = 1536; }
    else if (z == 1) { if (blockIdx.x >= 16) return; src = Wo; dst = WoT; R = 512; Cc = 512; }
    else             { if (blockIdx.x >= 32) return;
                       src = x + (long)(z-2)*NC*NTOK; dst = xsb + (long)(z-2)*NTOK*NC; R = NC; Cc = NTOK; }
    int c0 = blockIdx.x * 32, r0 = blockIdx.y * 32;
    int tx = threadIdx.x, ty = threadIdx.y;
    #pragma unroll
    for (int k = 0; k < 4; ++k)
        tile[ty + 8*k][tx] = src[(long)(r0 + ty + 8*k) * Cc + c0 + tx];
    __syncthreads();
    #pragma unroll
    for (int k = 0; k < 4; ++k)
        dst[(long)(c0 + ty + 8*k) * R + r0 + tx] = f2b(tile[tx][ty + 8*k]);
}

// ---- QKV projection v2: 256x256 tile, BK=64, double-buffered DMA, counted vmcnt ----
__global__ __launch_bounds__(512, 2) void gemm_qkv(const u16* __restrict__ WpT, const u16* __restrict__ xsb,
                                                   const float* __restrict__ bp,
                                                   u16* __restrict__ qg, u16* __restrict__ kg, u16* __restrict__ vg)
{
    __shared__ union SmU {
        struct { u16 As[2][256][64]; u16 Bs[2][256][64]; } s;   // 128 KB dbuf, DMA-linear, XOR-swizzled cols
        u16 Os[8][64][72];                                      // 72 KB epilogue overlay
    } sm;
    const int tid = threadIdx.x;
    // XCD-aware bijective swizzle: 192 blocks = 8 XCDs x 24
    const int raw = blockIdx.x;
    const int L = (raw & 7) * 24 + (raw >> 3);
    const int mb = L % 6, nb = L / 6;
    const int m0 = mb * 256;             // qkv column tile
    const int n0 = nb * 256;             // token tile
    const int w = tid >> 6, lane = tid & 63, quad = lane >> 4, lc = lane & 15;
    const int mo = (w & 1) * 128, no = (w >> 1) * 64;
    const int sw8 = (((lane & 7) ^ (lane >> 3)) << 3);   // per-lane swizzled 16B-block col offset
    const int xs = lc & 7;
    const int srow = (lane >> 3);

    f32x4 acc[8][4] = {};

    // stage tile 0 into buffer 0: 8 gll16/wave (4 A-rows-of-8 + 4 B-rows-of-8)
    #pragma unroll
    for (int p = 0; p < 4; ++p) {
        int row = w*32 + p*8 + srow;
        gll16(&WpT[(long)(m0 + row) * NC + 0 + sw8], &sm.s.As[0][w*32 + p*8][0]);
        gll16(&xsb[(long)(n0 + row) * NC + 0 + sw8], &sm.s.Bs[0][w*32 + p*8][0]);
    }

    for (int t = 0; t < 8; ++t) {
        if (t < 7) {
            const long kk = (long)(t + 1) * 64;
            const int nbuf = (t + 1) & 1;
            #pragma unroll
            for (int p = 0; p < 4; ++p) {
                int row = w*32 + p*8 + srow;
                gll16(&WpT[(long)(m0 + row) * NC + kk + sw8], &sm.s.As[nbuf][w*32 + p*8][0]);
                gll16(&xsb[(long)(n0 + row) * NC + kk + sw8], &sm.s.Bs[nbuf][w*32 + p*8][0]);
            }
            asm volatile("s_waitcnt vmcnt(8)" ::: "memory");   // tile t's 8 done; t+1's 8 stay in flight
        } else {
            asm volatile("s_waitcnt vmcnt(0)" ::: "memory");   // last tile: drain
        }
        __builtin_amdgcn_s_barrier();            // all waves: tile t fully staged
        __builtin_amdgcn_sched_barrier(0);       // keep ds_reads below the barrier

        const int cb = t & 1;
        #pragma unroll
        for (int ks = 0; ks < 2; ++ks) {
            bf16x8 af[8], bfr[4];
            #pragma unroll
            for (int mt = 0; mt < 8; ++mt)
                af[mt] = *(const bf16x8*)&sm.s.As[cb][mo + mt*16 + lc][((ks*4 + quad) ^ xs) << 3];
            #pragma unroll
            for (int nt = 0; nt < 4; ++nt)
                bfr[nt] = *(const bf16x8*)&sm.s.Bs[cb][no + nt*16 + lc][((ks*4 + quad) ^ xs) << 3];
            __builtin_amdgcn_s_setprio(1);
            #pragma unroll
            for (int mt = 0; mt < 8; ++mt)
                #pragma unroll
                for (int nt = 0; nt < 4; ++nt)
                    acc[mt][nt] = __builtin_amdgcn_mfma_f32_16x16x32_bf16(af[mt], bfr[nt], acc[mt][nt], 0, 0, 0);
            __builtin_amdgcn_s_setprio(0);
        }
        __builtin_amdgcn_s_barrier();            // all waves done reading buf[t&1]
    }

    // ---- epilogue: wave owns one 128-wide q/k/v panel of one head ----
    const int bb = n0 >> 10;              // batch
    const int nblk = n0 & 1023;           // token base within batch
    const int pb = (m0 + mo) >> 7;        // 128-col panel id, 0..11
    const int h = pb / 3;
    const int sel = pb % 3;               // 0=q 1=k 2=v (wave-uniform)
    const long bhbase = (long)(bb * NHEADS + h);

    #pragma unroll
    for (int mh = 0; mh < 2; ++mh) {
        const int d0 = mh * 64;
        #pragma unroll
        for (int mt4 = 0; mt4 < 4; ++mt4) {
            int mt = mh*4 + mt4;
            int cq0 = m0 + mo + mt*16 + quad*4;
            float b0 = bp[cq0+0], b1 = bp[cq0+1], b2 = bp[cq0+2], b3 = bp[cq0+3];
            #pragma unroll
            for (int nt = 0; nt < 4; ++nt) {
                f32x4 a = acc[mt][nt];
                int nl = nt*16 + lc;
                int ml = mt4*16 + quad*4;
                u16 e0 = f2b(a[0]+b0), e1 = f2b(a[1]+b1), e2 = f2b(a[2]+b2), e3 = f2b(a[3]+b3);
                if (sel == 2) {
                    sm.Os[w][ml+0][nl] = e0; sm.Os[w][ml+1][nl] = e1;
                    sm.Os[w][ml+2][nl] = e2; sm.Os[w][ml+3][nl] = e3;
                } else {
                    sm.Os[w][nl][ml+0] = e0; sm.Os[w][nl][ml+1] = e1;
                    sm.Os[w][nl][ml+2] = e2; sm.Os[w][nl][ml+3] = e3;
                }
            }
        }
        __builtin_amdgcn_sched_barrier(0);   // pin store->load order (wave-local LDS is in-order)

        if (sel == 2) {
            #pragma unroll
            for (int pass = 0; pass < 8; ++pass) {
                int ml  = pass*8 + srow;
                int nl0 = (lane & 7) * 8;
                bf16x8 vv = *(const bf16x8*)&sm.Os[w][ml][nl0];
                *(bf16x8*)&vg[((bhbase*DKH + d0 + ml) << 10) + nblk + no + sw8] = vv;
            }
        } else if (sel == 1) {
            #pragma unroll
            for (int pass = 0; pass < 8; ++pass) {
                int nl  = pass*8 + srow;
                int ml0 = (lane & 7) * 8;
                bf16x8 vv = *(const bf16x8*)&sm.Os[w][nl][ml0];
                *(bf16x8*)&kg[((bhbase*NTOK + nblk + no + nl) << 7) + d0 + sw8] = vv;
            }
        } else {
            #pragma unroll
            for (int pass = 0; pass < 8; ++pass) {
                int nl  = pass*8 + srow;
                int ml0 = (lane & 7) * 8;
                bf16x8 vv = *(const bf16x8*)&sm.Os[w][nl][ml0];
                *(bf16x8*)&qg[((bhbase*NTOK + nblk + no + nl) << 7) + d0 + ml0] = vv;
            }
        }
        __builtin_amdgcn_sched_barrier(0);   // wave-local: finish reads before next half rewrites Os
    }
}

// ---- flash attention v10: barrier-free, direct-from-L2 K/V loads (m169 pattern) ----
// R6 counters (MfmaUtil 11%, VALU 13%, HBM 4.8%, FETCH 12 MB) + R7 null (2-deep
// pipeline no help) => stall is the staging machinery itself: DMA->LDS->ds_read
// round-trip + 8-wave barrier convoy per tile. K/V are L2-resident (2 MB working
// set/XCD), so stage nothing: read fragments directly from kg/vtg (the global
// pre-swizzle matches the old LDS addressing verbatim). No __syncthreads at all;
// waves fully independent. LDS holds only wave-private Ps.
__global__ __launch_bounds__(512, 2) void attn(const u16* __restrict__ qg, const u16* __restrict__ kg,
                                               const u16* __restrict__ vtg, u16* __restrict__ ho)
{
    __shared__ u16 Ps[8][16][72];   // per-wave P[i][j], 18 KB
    const int tid = threadIdx.x;
    const int w = tid >> 6, lane = tid & 63, quad = lane >> 4, lc = lane & 15;
    // XCD-locality decode: id&7 = XCD residue; 4 (b,h) pairs per residue; 8 i-tiles per pair
    const int id = blockIdx.x;
    const int xcd = id & 7, rest = id >> 3, sub = rest & 3, bx = rest >> 2;
    const int pr = xcd + sub*8;
    const int b = pr >> 2, h = pr & 3;
    const int i0 = bx*128 + w*16;
    const long bh = (long)(b * NHEADS + h) << 17;   // *(1024*128)
    const u16* qb = qg + bh;
    const u16* kb = kg + bh;
    const u16* vb = vtg + bh;
    const float SL2E = 0.08838834764831845f * 1.4426950408889634f;  // scale * log2(e)

    bf16x8 qf[4];
    #pragma unroll
    for (int ks = 0; ks < 4; ++ks)
        qf[ks] = *(const bf16x8*)&qb[(long)(i0 + lc) * DKH + ks*32 + quad*8];

    f32x4 o[8] = {};
    float lsum = 0.f;
    const int xs = lc & 7;

    #pragma unroll 2
    for (int t = 0; t < 16; ++t) {
        const u16* Kt = kb + (long)t * 64 * 128;   // 64-j tile, rows [0,64) x 128 d (pre-swizzled 16B blocks)
        const u16* Vt = vb + t * 64;               // 64-j window within rows of 1024 (pre-swizzled)

        // load all 16 K fragments (independent, 16-deep in flight, L2-served)
        bf16x8 kf[16];
        #pragma unroll
        for (int ks = 0; ks < 4; ++ks)
            #pragma unroll
            for (int jt = 0; jt < 4; ++jt)
                kf[ks*4 + jt] = *(const bf16x8*)&Kt[(jt*16 + lc)*128 + (((ks*4 + quad) ^ xs) << 3)];

        // S^T = K Q^T: C rows = j, cols = i (lc)
        f32x4 s[4] = {};
        #pragma unroll
        for (int ks = 0; ks < 4; ++ks)
            #pragma unroll
            for (int jt = 0; jt < 4; ++jt)
                s[jt] = __builtin_amdgcn_mfma_f32_16x16x32_bf16(kf[ks*4 + jt], qf[ks], s[jt], 0, 0, 0);

        // softmax, no max subtraction (bounded logits), lane-local row sums
        #pragma unroll
        for (int jt = 0; jt < 4; ++jt) {
            float p0 = __builtin_amdgcn_exp2f(s[jt][0] * SL2E);
            float p1 = __builtin_amdgcn_exp2f(s[jt][1] * SL2E);
            float p2 = __builtin_amdgcn_exp2f(s[jt][2] * SL2E);
            float p3 = __builtin_amdgcn_exp2f(s[jt][3] * SL2E);
            lsum += (p0 + p1) + (p2 + p3);
            ushort4 pk;
            pk.x = f2b(p0); pk.y = f2b(p1); pk.z = f2b(p2); pk.w = f2b(p3);
            *(ushort4*)&Ps[w][lc][jt*16 + quad*4] = pk;   // P[i=lc][j-run]
        }
        __builtin_amdgcn_sched_barrier(0);  // wave-private Ps: pin write->read order

        // O^T += V^T P^T: A = V-frag (d rows, direct from L2), B = P-frag
        #pragma unroll
        for (int ks2 = 0; ks2 < 2; ++ks2) {
            bf16x8 pf = *(const bf16x8*)&Ps[w][lc][ks2*32 + quad*8];
            #pragma unroll
            for (int dt = 0; dt < 8; ++dt) {
                bf16x8 vf = *(const bf16x8*)&Vt[((long)(dt*16 + lc) << 10) + (((ks2*4 + quad) ^ xs) << 3)];
                o[dt] = __builtin_amdgcn_mfma_f32_16x16x32_bf16(vf, pf, o[dt], 0, 0, 0);
            }
        }
    }

    // final l reduction across quads (lanes sharing i=lc)
    lsum += __shfl_xor(lsum, 16);
    lsum += __shfl_xor(lsum, 32);
    float inv = 1.0f / lsum;

    #pragma unroll
    for (int dt = 0; dt < 8; ++dt) {
        ushort4 pk;
        pk.x = f2b(o[dt][0] * inv); pk.y = f2b(o[dt][1] * inv);
        pk.z = f2b(o[dt][2] * inv); pk.w = f2b(o[dt][3] * inv);
        *(ushort4*)&ho[(long)(b*NTOK + i0 + lc) * NC + h*DKH + dt*16 + quad*4] = pk;
    }
}

// ---- output projection + bias + fp32 residual, 128m x 64n tiles, DMA staging ----
__global__ __launch_bounds__(256) void gemm_out(const u16* __restrict__ WoT, const u16* __restrict__ ho,
                                                const float* __restrict__ bo, const float* __restrict__ xin,
                                                float* __restrict__ dout)
{
    __shared__ struct { u16 As[128][64]; u16 Bs[64][64]; } sm;   // 24 KB
    const int tid = threadIdx.x;
    const int m0 = blockIdx.x * 128;     // out-channel tile
    const int n0 = blockIdx.y * 64;      // token tile
    const int w = tid >> 6, lane = tid & 63, quad = lane >> 4, lc = lane & 15;
    const int mo = (w & 1) * 64, no = (w >> 1) * 32;
    const int sw8 = (((lane & 7) ^ (lane >> 3)) << 3);
    const int xs = lc & 7;

    f32x4 acc[4][2] = {};

    for (int k0 = 0; k0 < NC; k0 += 64) {
        __syncthreads();
        #pragma unroll
        for (int p = 0; p < 4; ++p) {
            int row = w*32 + p*8 + (lane >> 3);
            gll16(&WoT[(long)(m0 + row) * NC + k0 + sw8], &sm.As[w*32 + p*8][0]);
        }
        #pragma unroll
        for (int p = 0; p < 2; ++p) {
            int row = w*16 + p*8 + (lane >> 3);
            gll16(&ho[(long)(n0 + row) * NC + k0 + sw8], &sm.Bs[w*16 + p*8][0]);
        }
        __syncthreads();
        #pragma unroll
        for (int ks = 0; ks < 2; ++ks) {
            bf16x8 af[4], bfr[2];
            #pragma unroll
            for (int t = 0; t < 4; ++t)
                af[t] = *(const bf16x8*)&sm.As[mo + t*16 + lc][((ks*4 + quad) ^ xs) << 3];
            #pragma unroll
            for (int t = 0; t < 2; ++t)
                bfr[t] = *(const bf16x8*)&sm.Bs[no + t*16 + lc][((ks*4 + quad) ^ xs) << 3];
            #pragma unroll
            for (int mt = 0; mt < 4; ++mt)
                #pragma unroll
                for (int nt = 0; nt < 2; ++nt)
                    acc[mt][nt] = __builtin_amdgcn_mfma_f32_16x16x32_bf16(af[mt], bfr[nt], acc[mt][nt], 0, 0, 0);
        }
    }

    const int bb = n0 >> 10;
    #pragma unroll
    for (int mt = 0; mt < 4; ++mt) {
        int cc0 = m0 + mo + mt*16 + quad*4;
        float b0 = bo[cc0+0], b1 = bo[cc0+1], b2 = bo[cc0+2], b3 = bo[cc0+3];
        #pragma unroll
        for (int nt = 0; nt < 2; ++nt) {
            int nl = (n0 + no + nt*16 + lc) & (NTOK - 1);
            f32x4 a = acc[mt][nt];
            long ix = ((long)(bb*NC + cc0) << 10) + nl;
            dout[ix]             = a[0] + b0 + xin[ix];
            dout[ix + (1 << 10)] = a[1] + b1 + xin[ix + (1 << 10)];
            dout[ix + (2 << 10)] = a[2] + b2 + xin[ix + (2 << 10)];
            dout[ix + (3 << 10)] = a[3] + b3 + xin[ix + (3 << 10)];
        }
    }
}

extern "C" void kernel_launch(void* const* d_in, const int* in_sizes, int n_in,
                              void* d_out, int out_size, void* d_ws, size_t ws_size,
                              hipStream_t stream)
{
    (void)in_sizes; (void)n_in; (void)out_size; (void)ws_size;
    const float* x  = (const float*)d_in[0];
    const float* Wp = (const float*)d_in[1];
    const float* bp = (const float*)d_in[2];
    const float* Wo = (const float*)d_in[3];
    const float* bo = (const float*)d_in[4];
    float* out = (float*)d_out;

    // workspace layout (u16 elements), total ~42 MiB
    u16* ws  = (u16*)d_ws;
    u16* xsb = ws;                                   // [8192][512] bf16
    u16* WpT = xsb + (long)NB * NTOK * NC;           // [1536][512]
    u16* WoT = WpT + 1536L * 512;                    // [512][512]
    u16* qg  = WoT + 512L * 512;                     // [8][4][1024][128]
    u16* kg  = qg + (long)NB * NHEADS * NTOK * DKH;  // [8][4][1024][128]  (swizzled)
    u16* vtg = kg + (long)NB * NHEADS * NTOK * DKH;  // [8][4][128][1024]  (V transposed, swizzled)
    u16* ho  = vtg + (long)NB * NHEADS * NTOK * DKH; // [8192][512]

    prep<<<dim3(48, 16, 10), dim3(32, 8), 0, stream>>>(x, Wp, Wo, xsb, WpT, WoT);
    gemm_qkv<<<dim3(192), 512, 0, stream>>>(WpT, xsb, bp, qg, kg, vtg);
    attn<<<dim3(256), 512, 0, stream>>>(qg, kg, vtg, ho);
    gemm_out<<<dim3(NC/128, (NB*NTOK)/64), 256, 0, stream>>>(WoT, ho, bo, x, out);
}

// Round 9
// 139.479 us; speedup vs baseline: 1.1544x; 1.1544x over previous
//
#include <hip/hip_runtime.h>

#define NB 8
#define NC 512
#define NTOK 1024
#define NHEADS 4
#define DKH 128

typedef unsigned short u16;
typedef __attribute__((ext_vector_type(8))) short bf16x8;   // 8 bf16 (4 VGPRs)
typedef __attribute__((ext_vector_type(4))) float f32x4;

__device__ inline u16 f2b(float f) {
    union { float f; unsigned u; } v; v.f = f;
    unsigned r = v.u + 0x7fffu + ((v.u >> 16) & 1u);   // RNE
    return (u16)(r >> 16);
}

// async global->LDS DMA, 16B per lane; LDS dest = wave-uniform base + lane*16
__device__ __forceinline__ void gll16(const u16* g, u16* l) {
    __builtin_amdgcn_global_load_lds((const __attribute__((address_space(1))) unsigned*)g,
                                     (__attribute__((address_space(3))) unsigned*)l, 16, 0, 0);
}

// ---- fused prep: 3 transpose+convert jobs in one launch ----
// z=0: Wp[512][1536] -> WpT[1536][512]; z=1: Wo[512][512] -> WoT[512][512];
// z>=2: x batch (z-2) [512][1024] -> xsb [1024][512]
__global__ __launch_bounds__(256) void prep(const float* __restrict__ x, const float* __restrict__ Wp,
                                            const float* __restrict__ Wo,
                                            u16* __restrict__ xsb, u16* __restrict__ WpT, u16* __restrict__ WoT)
{
    __shared__ float tile[32][33];
    const int z = blockIdx.z;
    const float* src; u16* dst; int R, Cc;
    if (z == 0)      { src = Wp; dst = WpT; R = 512; Cc = 1536; }
    else if (z == 1) { if (blockIdx.x >= 16) return; src = Wo; dst = WoT; R = 512; Cc = 512; }
    else             { if (blockIdx.x >= 32) return;
                       src = x + (long)(z-2)*NC*NTOK; dst = xsb + (long)(z-2)*NTOK*NC; R = NC; Cc = NTOK; }
    int c0 = blockIdx.x * 32, r0 = blockIdx.y * 32;
    int tx = threadIdx.x, ty = threadIdx.y;
    #pragma unroll
    for (int k = 0; k < 4; ++k)
        tile[ty + 8*k][tx] = src[(long)(r0 + ty + 8*k) * Cc + c0 + tx];
    __syncthreads();
    #pragma unroll
    for (int k = 0; k < 4; ++k)
        dst[(long)(c0 + ty + 8*k) * R + r0 + tx] = f2b(tile[tx][ty + 8*k]);
}

// ---- QKV projection v2: 256x256 tile, BK=64, double-buffered DMA, counted vmcnt ----
__global__ __launch_bounds__(512, 2) void gemm_qkv(const u16* __restrict__ WpT, const u16* __restrict__ xsb,
                                                   const float* __restrict__ bp,
                                                   u16* __restrict__ qg, u16* __restrict__ kg, u16* __restrict__ vg)
{
    __shared__ union SmU {
        struct { u16 As[2][256][64]; u16 Bs[2][256][64]; } s;   // 128 KB dbuf, DMA-linear, XOR-swizzled cols
        u16 Os[8][64][72];                                      // 72 KB epilogue overlay
    } sm;
    const int tid = threadIdx.x;
    // XCD-aware bijective swizzle: 192 blocks = 8 XCDs x 24
    const int raw = blockIdx.x;
    const int L = (raw & 7) * 24 + (raw >> 3);
    const int mb = L % 6, nb = L / 6;
    const int m0 = mb * 256;             // qkv column tile
    const int n0 = nb * 256;             // token tile
    const int w = tid >> 6, lane = tid & 63, quad = lane >> 4, lc = lane & 15;
    const int mo = (w & 1) * 128, no = (w >> 1) * 64;
    const int sw8 = (((lane & 7) ^ (lane >> 3)) << 3);   // per-lane swizzled 16B-block col offset
    const int xs = lc & 7;
    const int srow = (lane >> 3);

    f32x4 acc[8][4] = {};

    // stage tile 0 into buffer 0: 8 gll16/wave (4 A-rows-of-8 + 4 B-rows-of-8)
    #pragma unroll
    for (int p = 0; p < 4; ++p) {
        int row = w*32 + p*8 + srow;
        gll16(&WpT[(long)(m0 + row) * NC + 0 + sw8], &sm.s.As[0][w*32 + p*8][0]);
        gll16(&xsb[(long)(n0 + row) * NC + 0 + sw8], &sm.s.Bs[0][w*32 + p*8][0]);
    }

    for (int t = 0; t < 8; ++t) {
        if (t < 7) {
            const long kk = (long)(t + 1) * 64;
            const int nbuf = (t + 1) & 1;
            #pragma unroll
            for (int p = 0; p < 4; ++p) {
                int row = w*32 + p*8 + srow;
                gll16(&WpT[(long)(m0 + row) * NC + kk + sw8], &sm.s.As[nbuf][w*32 + p*8][0]);
                gll16(&xsb[(long)(n0 + row) * NC + kk + sw8], &sm.s.Bs[nbuf][w*32 + p*8][0]);
            }
            asm volatile("s_waitcnt vmcnt(8)" ::: "memory");   // tile t's 8 done; t+1's 8 stay in flight
        } else {
            asm volatile("s_waitcnt vmcnt(0)" ::: "memory");   // last tile: drain
        }
        __builtin_amdgcn_s_barrier();            // all waves: tile t fully staged
        __builtin_amdgcn_sched_barrier(0);       // keep ds_reads below the barrier

        const int cb = t & 1;
        #pragma unroll
        for (int ks = 0; ks < 2; ++ks) {
            bf16x8 af[8], bfr[4];
            #pragma unroll
            for (int mt = 0; mt < 8; ++mt)
                af[mt] = *(const bf16x8*)&sm.s.As[cb][mo + mt*16 + lc][((ks*4 + quad) ^ xs) << 3];
            #pragma unroll
            for (int nt = 0; nt < 4; ++nt)
                bfr[nt] = *(const bf16x8*)&sm.s.Bs[cb][no + nt*16 + lc][((ks*4 + quad) ^ xs) << 3];
            __builtin_amdgcn_s_setprio(1);
            #pragma unroll
            for (int mt = 0; mt < 8; ++mt)
                #pragma unroll
                for (int nt = 0; nt < 4; ++nt)
                    acc[mt][nt] = __builtin_amdgcn_mfma_f32_16x16x32_bf16(af[mt], bfr[nt], acc[mt][nt], 0, 0, 0);
            __builtin_amdgcn_s_setprio(0);
        }
        __builtin_amdgcn_s_barrier();            // all waves done reading buf[t&1]
    }

    // ---- epilogue: wave owns one 128-wide q/k/v panel of one head ----
    const int bb = n0 >> 10;              // batch
    const int nblk = n0 & 1023;           // token base within batch
    const int pb = (m0 + mo) >> 7;        // 128-col panel id, 0..11
    const int h = pb / 3;
    const int sel = pb % 3;               // 0=q 1=k 2=v (wave-uniform)
    const long bhbase = (long)(bb * NHEADS + h);

    #pragma unroll
    for (int mh = 0; mh < 2; ++mh) {
        const int d0 = mh * 64;
        #pragma unroll
        for (int mt4 = 0; mt4 < 4; ++mt4) {
            int mt = mh*4 + mt4;
            int cq0 = m0 + mo + mt*16 + quad*4;
            float b0 = bp[cq0+0], b1 = bp[cq0+1], b2 = bp[cq0+2], b3 = bp[cq0+3];
            #pragma unroll
            for (int nt = 0; nt < 4; ++nt) {
                f32x4 a = acc[mt][nt];
                int nl = nt*16 + lc;
                int ml = mt4*16 + quad*4;
                u16 e0 = f2b(a[0]+b0), e1 = f2b(a[1]+b1), e2 = f2b(a[2]+b2), e3 = f2b(a[3]+b3);
                if (sel == 2) {
                    sm.Os[w][ml+0][nl] = e0; sm.Os[w][ml+1][nl] = e1;
                    sm.Os[w][ml+2][nl] = e2; sm.Os[w][ml+3][nl] = e3;
                } else {
                    sm.Os[w][nl][ml+0] = e0; sm.Os[w][nl][ml+1] = e1;
                    sm.Os[w][nl][ml+2] = e2; sm.Os[w][nl][ml+3] = e3;
                }
            }
        }
        __builtin_amdgcn_sched_barrier(0);   // pin store->load order (wave-local LDS is in-order)

        if (sel == 2) {
            #pragma unroll
            for (int pass = 0; pass < 8; ++pass) {
                int ml  = pass*8 + srow;
                int nl0 = (lane & 7) * 8;
                bf16x8 vv = *(const bf16x8*)&sm.Os[w][ml][nl0];
                *(bf16x8*)&vg[((bhbase*DKH + d0 + ml) << 10) + nblk + no + sw8] = vv;
            }
        } else if (sel == 1) {
            #pragma unroll
            for (int pass = 0; pass < 8; ++pass) {
                int nl  = pass*8 + srow;
                int ml0 = (lane & 7) * 8;
                bf16x8 vv = *(const bf16x8*)&sm.Os[w][nl][ml0];
                *(bf16x8*)&kg[((bhbase*NTOK + nblk + no + nl) << 7) + d0 + sw8] = vv;
            }
        } else {
            #pragma unroll
            for (int pass = 0; pass < 8; ++pass) {
                int nl  = pass*8 + srow;
                int ml0 = (lane & 7) * 8;
                bf16x8 vv = *(const bf16x8*)&sm.Os[w][nl][ml0];
                *(bf16x8*)&qg[((bhbase*NTOK + nblk + no + nl) << 7) + d0 + ml0] = vv;
            }
        }
        __builtin_amdgcn_sched_barrier(0);   // wave-local: finish reads before next half rewrites Os
    }
}

// ---- flash attention v12: 256 blocks x 1024 threads = 16 waves/CU = 4 waves/SIMD ----
// First TLP test: every prior variant ran 2 waves/SIMD and stalled ~70% with all
// pipes idle. 16 waves = 8 i-groups x 2 j-halves; each half walks its 8 j-tiles
// (K dbuf + single V, counted vmcnt(2) keeps K-prefetch in flight). Same total
// LDS traffic / DMA / MFMA as v4 -> isolates the TLP axis. In-LDS unnormalized-O
// merge at the end (static accumulator indices, wave-uniform jh branch; rule #20).
__global__ __launch_bounds__(1024, 4) void attn(const u16* __restrict__ qg, const u16* __restrict__ kg,
                                                const u16* __restrict__ vtg, u16* __restrict__ ho)
{
    __shared__ union AS {
        struct { u16 Ks[2][2][64*128]; u16 Vt[2][128*64]; u16 Ps[16][16][72]; } m;  // 64+32+36 = 132 KB
        struct { float Om[8][16][132]; float Lm[8][16]; } g;                        // ~68 KB merge overlay
    } sm;
    const int tid = threadIdx.x;
    const int w = tid >> 6, lane = tid & 63, quad = lane >> 4, lc = lane & 15;
    const int ig = w & 7, jh = w >> 3;       // i-group (0..7), j-half (0..1)
    // XCD-locality decode: id&7 = XCD residue; 4 (b,h) pairs per residue; 8 i-tiles per pair
    const int id = blockIdx.x;
    const int xcd = id & 7, rest = id >> 3, sub = rest & 3, bx = rest >> 2;
    const int pr = xcd + sub*8;
    const int b = pr >> 2, h = pr & 3;
    const int i0 = bx*128 + ig*16;
    const long bh = (long)(b * NHEADS + h) << 17;   // *(1024*128)
    const u16* qb = qg + bh;
    const u16* kb = kg + bh;
    const u16* vb = vtg + bh;
    const float SL2E = 0.08838834764831845f * 1.4426950408889634f;  // scale * log2(e)

    bf16x8 qf[4];
    #pragma unroll
    for (int ks = 0; ks < 4; ++ks)
        qf[ks] = *(const bf16x8*)&qb[(long)(i0 + lc) * DKH + ks*32 + quad*8];

    f32x4 o[8] = {};
    float lsum = 0.f;
    const int xs = lc & 7;
    const long jbase = (long)jh * 8;   // this half's first j-tile index

    // prologue: each half's 8 waves stage K tile (jbase) into Ks[jh][0]
    #pragma unroll
    for (int p = 0; p < 2; ++p) {
        int ck = (ig*2 + p)*64 + lane;
        gll16(&kb[jbase*64*128 + (long)ck*8], &sm.m.Ks[jh][0][(ig*2 + p)*512]);
    }

    for (int t = 0; t < 8; ++t) {
        __syncthreads();   // drains vmcnt(0): K(t) staged; V buffer free (prev PV done everywhere)
        const long jo = (jbase + t) * 64;
        // issue V(t) into Vt[jh]  (FIFO: V,V first)
        #pragma unroll
        for (int p = 0; p < 2; ++p) {
            int ck = (ig*2 + p)*64 + lane;
            gll16(&vb[(((long)(ck >> 3)) << 10) + jo + (ck & 7)*8], &sm.m.Vt[jh][(ig*2 + p)*512]);
        }
        // issue K(t+1) into the other K buffer (stays in flight across the V-barrier)
        if (t < 7) {
            const long jo2 = (jbase + t + 1) * 64;
            #pragma unroll
            for (int p = 0; p < 2; ++p) {
                int ck = (ig*2 + p)*64 + lane;
                gll16(&kb[jo2*128 + (long)ck*8], &sm.m.Ks[jh][(t+1)&1][(ig*2 + p)*512]);
            }
        }
        __builtin_amdgcn_sched_barrier(0);   // pin DMA issue order above compute

        const u16* K = sm.m.Ks[jh][t&1];

        // S^T = K Q^T: C rows = j (this half's 64), cols = i (lc)
        f32x4 s[4] = {};
        #pragma unroll
        for (int ks = 0; ks < 4; ++ks)
            #pragma unroll
            for (int jt = 0; jt < 4; ++jt) {
                bf16x8 kf = *(const bf16x8*)&K[(jt*16 + lc)*128 + (((ks*4 + quad) ^ xs) << 3)];
                s[jt] = __builtin_amdgcn_mfma_f32_16x16x32_bf16(kf, qf[ks], s[jt], 0, 0, 0);
            }

        // softmax, no max subtraction (bounded logits), lane-local row sums
        #pragma unroll
        for (int jt = 0; jt < 4; ++jt) {
            float p0 = __builtin_amdgcn_exp2f(s[jt][0] * SL2E);
            float p1 = __builtin_amdgcn_exp2f(s[jt][1] * SL2E);
            float p2 = __builtin_amdgcn_exp2f(s[jt][2] * SL2E);
            float p3 = __builtin_amdgcn_exp2f(s[jt][3] * SL2E);
            lsum += (p0 + p1) + (p2 + p3);
            ushort4 pk;
            pk.x = f2b(p0); pk.y = f2b(p1); pk.z = f2b(p2); pk.w = f2b(p3);
            *(ushort4*)&sm.m.Ps[w][lc][jt*16 + quad*4] = pk;   // P[i=lc][j-run]
        }
        __builtin_amdgcn_sched_barrier(0);  // wave-private Ps: pin write->read order

        // own V chunks landed (K(t+1)'s 2 ops stay in flight), then all-waves V barrier
        if (t < 7) { asm volatile("s_waitcnt vmcnt(2)" ::: "memory"); }
        else       { asm volatile("s_waitcnt vmcnt(0)" ::: "memory"); }
        __builtin_amdgcn_s_barrier();

        // O^T += V^T P^T: A = V-frag (d rows), B = P-frag
        const u16* V = sm.m.Vt[jh];
        #pragma unroll
        for (int ks2 = 0; ks2 < 2; ++ks2) {
            bf16x8 pf = *(const bf16x8*)&sm.m.Ps[w][lc][ks2*32 + quad*8];
            #pragma unroll
            for (int dt = 0; dt < 8; ++dt) {
                bf16x8 vf = *(const bf16x8*)&V[(dt*16 + lc)*64 + (((ks2*4 + quad) ^ xs) << 3)];
                o[dt] = __builtin_amdgcn_mfma_f32_16x16x32_bf16(vf, pf, o[dt], 0, 0, 0);
            }
        }
    }

    // reduce partial lsum across quads (lanes sharing i=lc within this half)
    lsum += __shfl_xor(lsum, 16);
    lsum += __shfl_xor(lsum, 32);

    // ---- j-half merge via LDS overlay (Ks/Vt/Ps all dead) ----
    __syncthreads();
    if (jh == 1) {
        #pragma unroll
        for (int dt = 0; dt < 8; ++dt)
            *(f32x4*)&sm.g.Om[ig][lc][dt*16 + quad*4] = o[dt];
        if (quad == 0) sm.g.Lm[ig][lc] = lsum;
    }
    __syncthreads();
    if (jh == 0) {
        float lt = lsum + sm.g.Lm[ig][lc];
        float inv = 1.0f / lt;
        #pragma unroll
        for (int dt = 0; dt < 8; ++dt) {
            f32x4 part = *(const f32x4*)&sm.g.Om[ig][lc][dt*16 + quad*4];
            f32x4 tot = o[dt] + part;
            ushort4 pk;
            pk.x = f2b(tot[0] * inv); pk.y = f2b(tot[1] * inv);
            pk.z = f2b(tot[2] * inv); pk.w = f2b(tot[3] * inv);
            *(ushort4*)&ho[(long)(b*NTOK + i0 + lc) * NC + h*DKH + dt*16 + quad*4] = pk;
        }
    }
}

// ---- output projection + bias + fp32 residual, 128m x 64n tiles, DMA staging ----
__global__ __launch_bounds__(256) void gemm_out(const u16* __restrict__ WoT, const u16* __restrict__ ho,
                                                const float* __restrict__ bo, const float* __restrict__ xin,
                                                float* __restrict__ dout)
{
    __shared__ struct { u16 As[128][64]; u16 Bs[64][64]; } sm;   // 24 KB
    const int tid = threadIdx.x;
    const int m0 = blockIdx.x * 128;     // out-channel tile
    const int n0 = blockIdx.y * 64;      // token tile
    const int w = tid >> 6, lane = tid & 63, quad = lane >> 4, lc = lane & 15;
    const int mo = (w & 1) * 64, no = (w >> 1) * 32;
    const int sw8 = (((lane & 7) ^ (lane >> 3)) << 3);
    const int xs = lc & 7;

    f32x4 acc[4][2] = {};

    for (int k0 = 0; k0 < NC; k0 += 64) {
        __syncthreads();
        #pragma unroll
        for (int p = 0; p < 4; ++p) {
            int row = w*32 + p*8 + (lane >> 3);
            gll16(&WoT[(long)(m0 + row) * NC + k0 + sw8], &sm.As[w*32 + p*8][0]);
        }
        #pragma unroll
        for (int p = 0; p < 2; ++p) {
            int row = w*16 + p*8 + (lane >> 3);
            gll16(&ho[(long)(n0 + row) * NC + k0 + sw8], &sm.Bs[w*16 + p*8][0]);
        }
        __syncthreads();
        #pragma unroll
        for (int ks = 0; ks < 2; ++ks) {
            bf16x8 af[4], bfr[2];
            #pragma unroll
            for (int t = 0; t < 4; ++t)
                af[t] = *(const bf16x8*)&sm.As[mo + t*16 + lc][((ks*4 + quad) ^ xs) << 3];
            #pragma unroll
            for (int t = 0; t < 2; ++t)
                bfr[t] = *(const bf16x8*)&sm.Bs[no + t*16 + lc][((ks*4 + quad) ^ xs) << 3];
            #pragma unroll
            for (int mt = 0; mt < 4; ++mt)
                #pragma unroll
                for (int nt = 0; nt < 2; ++nt)
                    acc[mt][nt] = __builtin_amdgcn_mfma_f32_16x16x32_bf16(af[mt], bfr[nt], acc[mt][nt], 0, 0, 0);
        }
    }

    const int bb = n0 >> 10;
    #pragma unroll
    for (int mt = 0; mt < 4; ++mt) {
        int cc0 = m0 + mo + mt*16 + quad*4;
        float b0 = bo[cc0+0], b1 = bo[cc0+1], b2 = bo[cc0+2], b3 = bo[cc0+3];
        #pragma unroll
        for (int nt = 0; nt < 2; ++nt) {
            int nl = (n0 + no + nt*16 + lc) & (NTOK - 1);
            f32x4 a = acc[mt][nt];
            long ix = ((long)(bb*NC + cc0) << 10) + nl;
            dout[ix]             = a[0] + b0 + xin[ix];
            dout[ix + (1 << 10)] = a[1] + b1 + xin[ix + (1 << 10)];
            dout[ix + (2 << 10)] = a[2] + b2 + xin[ix + (2 << 10)];
            dout[ix + (3 << 10)] = a[3] + b3 + xin[ix + (3 << 10)];
        }
    }
}

extern "C" void kernel_launch(void* const* d_in, const int* in_sizes, int n_in,
                              void* d_out, int out_size, void* d_ws, size_t ws_size,
                              hipStream_t stream)
{
    (void)in_sizes; (void)n_in; (void)out_size; (void)ws_size;
    const float* x  = (const float*)d_in[0];
    const float* Wp = (const float*)d_in[1];
    const float* bp = (const float*)d_in[2];
    const float* Wo = (const float*)d_in[3];
    const float* bo = (const float*)d_in[4];
    float* out = (float*)d_out;

    // workspace layout (u16 elements), total ~42 MiB
    u16* ws  = (u16*)d_ws;
    u16* xsb = ws;                                   // [8192][512] bf16
    u16* WpT = xsb + (long)NB * NTOK * NC;           // [1536][512]
    u16* WoT = WpT + 1536L * 512;                    // [512][512]
    u16* qg  = WoT + 512L * 512;                     // [8][4][1024][128]
    u16* kg  = qg + (long)NB * NHEADS * NTOK * DKH;  // [8][4][1024][128]  (swizzled)
    u16* vtg = kg + (long)NB * NHEADS * NTOK * DKH;  // [8][4][128][1024]  (V transposed, swizzled)
    u16* ho  = vtg + (long)NB * NHEADS * NTOK * DKH; // [8192][512]

    prep<<<dim3(48, 16, 10), dim3(32, 8), 0, stream>>>(x, Wp, Wo, xsb, WpT, WoT);
    gemm_qkv<<<dim3(192), 512, 0, stream>>>(WpT, xsb, bp, qg, kg, vtg);
    attn<<<dim3(256), 1024, 0, stream>>>(qg, kg, vtg, ho);
    gemm_out<<<dim3(NC/128, (NB*NTOK)/64), 256, 0, stream>>>(WoT, ho, bo, x, out);
}